// Round 4
// baseline (91.821 us; speedup 1.0000x reference)
//
#include <hip/hip_runtime.h>

typedef float f32x2 __attribute__((ext_vector_type(2)));
typedef float f32x4 __attribute__((ext_vector_type(4)));

#define BATCH   8
#define NPTS    8192
#define THREADS 256
#define QPT     8                      // queries per thread
#define QBLK    (THREADS * QPT)        // 2048 queries per block
#define NQB     (NPTS / QBLK)          // 4 query-blocks per (batch,dir)
#define TSPLIT  8                      // target-dimension split
#define TSLICE  (NPTS / TSPLIT)        // 1024 targets per block (whole slice in LDS)
#define NQ_TOTAL (BATCH * 2 * NPTS)    // 131072 total queries

// Stage 1: for 2048 query points, min of (||b||^2 - 2 a.b) over a
// 1024-target slice. Whole slice staged SoA in LDS (16 KB, one barrier);
// candidates two-at-a-time via compiler-packed v_pk_fma_f32
// (__builtin_elementwise_fma), reduced with fused v_min3_f32.
__global__ __launch_bounds__(THREADS, 2) void chamfer_stage1(
    const float* __restrict__ A,   // [B, N, 3] "input"
    const float* __restrict__ Bp,  // [B, M, 3] "output"
    float* __restrict__ partial)   // [TSPLIT][NQ_TOTAL]
{
    __shared__ __align__(16) float tx[TSLICE];
    __shared__ __align__(16) float ty[TSLICE];
    __shared__ __align__(16) float tz[TSLICE];
    __shared__ __align__(16) float tw[TSLICE];

    const int bid = blockIdx.x;
    const int ts  = bid & (TSPLIT - 1);          // 3 bits
    const int qb  = (bid >> 3) & (NQB - 1);      // 2 bits
    const int bd  = bid >> 5;                    // 0..15  (batch*2 + dir)
    const int b   = bd >> 1;
    const int dir = bd & 1;

    const float* Q = (dir == 0) ? (A  + (size_t)b * NPTS * 3)
                                : (Bp + (size_t)b * NPTS * 3);
    const float* T = (dir == 0) ? (Bp + (size_t)b * NPTS * 3)
                                : (A  + (size_t)b * NPTS * 3);

    const int tid = threadIdx.x;

    // Stage the target slice (SoA) into LDS.
    const int tbase = ts * TSLICE;
#pragma unroll
    for (int u = 0; u < TSLICE / THREADS; ++u) {
        const int t = u * THREADS + tid;
        const int j = tbase + t;
        const float x = T[j * 3 + 0];
        const float y = T[j * 3 + 1];
        const float z = T[j * 3 + 2];
        tx[t] = x; ty[t] = y; tz[t] = z;
        tw[t] = fmaf(z, z, fmaf(y, y, x * x));
    }

    f32x2 qx[QPT], qy[QPT], qz[QPT];
    float aa[QPT], mn01[QPT], mn23[QPT];
#pragma unroll
    for (int k = 0; k < QPT; ++k) {
        const int q = qb * QBLK + k * THREADS + tid;
        const float x = Q[q * 3 + 0];
        const float y = Q[q * 3 + 1];
        const float z = Q[q * 3 + 2];
        aa[k] = x * x + y * y + z * z;
        const float x2 = -2.0f * x, y2 = -2.0f * y, z2 = -2.0f * z;
        qx[k] = (f32x2){x2, x2};
        qy[k] = (f32x2){y2, y2};
        qz[k] = (f32x2){z2, z2};
        mn01[k] = 3.4e38f;
        mn23[k] = 3.4e38f;
    }

    __syncthreads();

    for (int jj = 0; jj < TSLICE; jj += 4) {
        const f32x4 bx = *(const f32x4*)&tx[jj];   // uniform-addr broadcast reads
        const f32x4 by = *(const f32x4*)&ty[jj];
        const f32x4 bz = *(const f32x4*)&tz[jj];
        const f32x4 bw = *(const f32x4*)&tw[jj];
        const f32x2 bx01 = __builtin_shufflevector(bx, bx, 0, 1);
        const f32x2 bx23 = __builtin_shufflevector(bx, bx, 2, 3);
        const f32x2 by01 = __builtin_shufflevector(by, by, 0, 1);
        const f32x2 by23 = __builtin_shufflevector(by, by, 2, 3);
        const f32x2 bz01 = __builtin_shufflevector(bz, bz, 0, 1);
        const f32x2 bz23 = __builtin_shufflevector(bz, bz, 2, 3);
        const f32x2 bw01 = __builtin_shufflevector(bw, bw, 0, 1);
        const f32x2 bw23 = __builtin_shufflevector(bw, bw, 2, 3);
#pragma unroll
        for (int k = 0; k < QPT; ++k) {
            f32x2 c01 = __builtin_elementwise_fma(qx[k], bx01, bw01);
            c01 = __builtin_elementwise_fma(qy[k], by01, c01);
            c01 = __builtin_elementwise_fma(qz[k], bz01, c01);
            f32x2 c23 = __builtin_elementwise_fma(qx[k], bx23, bw23);
            c23 = __builtin_elementwise_fma(qy[k], by23, c23);
            c23 = __builtin_elementwise_fma(qz[k], bz23, c23);
            mn01[k] = fminf(fminf(c01.x, c01.y), mn01[k]);   // -> v_min3_f32
            mn23[k] = fminf(fminf(c23.x, c23.y), mn23[k]);   // -> v_min3_f32
        }
    }

#pragma unroll
    for (int k = 0; k < QPT; ++k) {
        const int q = qb * QBLK + k * THREADS + tid;
        const int qglobal = bd * NPTS + q;
        partial[(size_t)ts * NQ_TOTAL + qglobal] = fminf(mn01[k], mn23[k]) + aa[k];
    }
}

__device__ inline float wave_reduce_sum(float v) {
#pragma unroll
    for (int off = 32; off; off >>= 1) v += __shfl_down(v, off, 64);
    return v;
}

// Stage 2: combine TSPLIT partial mins per query, block-sum 256 queries.
__global__ __launch_bounds__(THREADS) void chamfer_stage2(
    const float* __restrict__ partial, float* __restrict__ blocksum)
{
    const int qglobal = blockIdx.x * THREADS + threadIdx.x;
    float m = 3.4e38f;
#pragma unroll
    for (int ts = 0; ts < TSPLIT; ++ts)
        m = fminf(m, partial[(size_t)ts * NQ_TOTAL + qglobal]);

    __shared__ float wsum[THREADS / 64];
    const float s = wave_reduce_sum(m);
    if ((threadIdx.x & 63) == 0) wsum[threadIdx.x >> 6] = s;
    __syncthreads();
    if (threadIdx.x == 0) {
        float t = 0.f;
#pragma unroll
        for (int w = 0; w < THREADS / 64; ++w) t += wsum[w];
        blocksum[blockIdx.x] = t;
    }
}

// Stage 3: deterministic final reduction of 512 block sums.
__global__ __launch_bounds__(THREADS) void chamfer_stage3(
    const float* __restrict__ blocksum, float* __restrict__ out)
{
    float v = blocksum[threadIdx.x] + blocksum[threadIdx.x + THREADS];
    __shared__ float wsum[THREADS / 64];
    const float s = wave_reduce_sum(v);
    if ((threadIdx.x & 63) == 0) wsum[threadIdx.x >> 6] = s;
    __syncthreads();
    if (threadIdx.x == 0) {
        float t = 0.f;
#pragma unroll
        for (int w = 0; w < THREADS / 64; ++w) t += wsum[w];
        out[0] = t;
    }
}

extern "C" void kernel_launch(void* const* d_in, const int* in_sizes, int n_in,
                              void* d_out, int out_size, void* d_ws, size_t ws_size,
                              hipStream_t stream) {
    const float* A  = (const float*)d_in[0];   // "input"  [8,8192,3]
    const float* Bp = (const float*)d_in[1];   // "output" [8,8192,3]
    float* out = (float*)d_out;

    float* partial  = (float*)d_ws;                          // TSPLIT*NQ_TOTAL floats = 4 MB
    float* blocksum = partial + (size_t)TSPLIT * NQ_TOTAL;   // 512 floats

    const int nblocks1 = BATCH * 2 * NQB * TSPLIT;           // 512
    chamfer_stage1<<<nblocks1, THREADS, 0, stream>>>(A, Bp, partial);

    const int nblocks2 = NQ_TOTAL / THREADS;                 // 512
    chamfer_stage2<<<nblocks2, THREADS, 0, stream>>>(partial, blocksum);

    chamfer_stage3<<<1, THREADS, 0, stream>>>(blocksum, out);
}

// Round 5
// 90.308 us; speedup vs baseline: 1.0168x; 1.0168x over previous
//
#include <hip/hip_runtime.h>

typedef float f32x2 __attribute__((ext_vector_type(2)));
typedef float f32x4 __attribute__((ext_vector_type(4)));

#define BATCH   8
#define NPTS    8192
#define THREADS 256
#define QPT     4                      // queries per thread
#define QBLK    (THREADS * QPT)        // 1024 queries per block
#define NQB     (NPTS / QBLK)          // 8 query-blocks per (batch,dir)
#define TSPLIT  16                     // target-dimension split
#define TSLICE  (NPTS / TSPLIT)        // 512 targets per block
#define NQ_TOTAL (BATCH * 2 * NPTS)    // 131072 total queries

// Init: fill per-query min array with +huge (valid float, any real dist^2 wins).
__global__ __launch_bounds__(THREADS) void chamfer_init(float* __restrict__ minarr) {
    minarr[blockIdx.x * THREADS + threadIdx.x] = 3.4e38f;
}

// Stage 1: for 1024 query points, min of (||b||^2 - 2 a.b) over a
// 512-target slice; result (+||a||^2) merged via atomicMin on int bits
// (exact & order-independent for nonnegative floats -> deterministic).
__global__ __launch_bounds__(THREADS) void chamfer_stage1(
    const float* __restrict__ A,   // [B, N, 3] "input"
    const float* __restrict__ Bp,  // [B, M, 3] "output"
    float* __restrict__ minarr)    // [NQ_TOTAL]
{
    __shared__ __align__(16) float tx[TSLICE];
    __shared__ __align__(16) float ty[TSLICE];
    __shared__ __align__(16) float tz[TSLICE];
    __shared__ __align__(16) float tw[TSLICE];

    const int bid = blockIdx.x;
    const int ts  = bid & (TSPLIT - 1);          // 4 bits
    const int qb  = (bid >> 4) & (NQB - 1);      // 3 bits
    const int bd  = bid >> 7;                    // 0..15  (batch*2 + dir)
    const int b   = bd >> 1;
    const int dir = bd & 1;

    const float* Q = (dir == 0) ? (A  + (size_t)b * NPTS * 3)
                                : (Bp + (size_t)b * NPTS * 3);
    const float* T = (dir == 0) ? (Bp + (size_t)b * NPTS * 3)
                                : (A  + (size_t)b * NPTS * 3);

    const int tid = threadIdx.x;

    // Stage the target slice (SoA) into LDS.
    const int tbase = ts * TSLICE;
#pragma unroll
    for (int u = 0; u < TSLICE / THREADS; ++u) {
        const int t = u * THREADS + tid;
        const int j = tbase + t;
        const float x = T[j * 3 + 0];
        const float y = T[j * 3 + 1];
        const float z = T[j * 3 + 2];
        tx[t] = x; ty[t] = y; tz[t] = z;
        tw[t] = fmaf(z, z, fmaf(y, y, x * x));
    }

    f32x2 qx[QPT], qy[QPT], qz[QPT];
    float aa[QPT], mn01[QPT], mn23[QPT];
#pragma unroll
    for (int k = 0; k < QPT; ++k) {
        const int q = qb * QBLK + k * THREADS + tid;
        const float x = Q[q * 3 + 0];
        const float y = Q[q * 3 + 1];
        const float z = Q[q * 3 + 2];
        aa[k] = x * x + y * y + z * z;
        const float x2 = -2.0f * x, y2 = -2.0f * y, z2 = -2.0f * z;
        qx[k] = (f32x2){x2, x2};
        qy[k] = (f32x2){y2, y2};
        qz[k] = (f32x2){z2, z2};
        mn01[k] = 3.4e38f;
        mn23[k] = 3.4e38f;
    }

    __syncthreads();

    for (int jj = 0; jj < TSLICE; jj += 4) {
        const f32x4 bx = *(const f32x4*)&tx[jj];   // uniform-addr broadcast reads
        const f32x4 by = *(const f32x4*)&ty[jj];
        const f32x4 bz = *(const f32x4*)&tz[jj];
        const f32x4 bw = *(const f32x4*)&tw[jj];
        const f32x2 bx01 = __builtin_shufflevector(bx, bx, 0, 1);
        const f32x2 bx23 = __builtin_shufflevector(bx, bx, 2, 3);
        const f32x2 by01 = __builtin_shufflevector(by, by, 0, 1);
        const f32x2 by23 = __builtin_shufflevector(by, by, 2, 3);
        const f32x2 bz01 = __builtin_shufflevector(bz, bz, 0, 1);
        const f32x2 bz23 = __builtin_shufflevector(bz, bz, 2, 3);
        const f32x2 bw01 = __builtin_shufflevector(bw, bw, 0, 1);
        const f32x2 bw23 = __builtin_shufflevector(bw, bw, 2, 3);
#pragma unroll
        for (int k = 0; k < QPT; ++k) {
            f32x2 c01 = __builtin_elementwise_fma(qx[k], bx01, bw01);
            c01 = __builtin_elementwise_fma(qy[k], by01, c01);
            c01 = __builtin_elementwise_fma(qz[k], bz01, c01);
            f32x2 c23 = __builtin_elementwise_fma(qx[k], bx23, bw23);
            c23 = __builtin_elementwise_fma(qy[k], by23, c23);
            c23 = __builtin_elementwise_fma(qz[k], bz23, c23);
            mn01[k] = fminf(fminf(c01.x, c01.y), mn01[k]);   // -> v_min3_f32
            mn23[k] = fminf(fminf(c23.x, c23.y), mn23[k]);   // -> v_min3_f32
        }
    }

#pragma unroll
    for (int k = 0; k < QPT; ++k) {
        const int q = qb * QBLK + k * THREADS + tid;
        const int qglobal = bd * NPTS + q;
        const float v = fminf(mn01[k], mn23[k]) + aa[k];     // dist^2 >= 0
        atomicMin((int*)&minarr[qglobal], __float_as_int(v));
    }
}

__device__ inline float wave_reduce_sum(float v) {
#pragma unroll
    for (int off = 32; off; off >>= 1) v += __shfl_down(v, off, 64);
    return v;
}

// Stage 2: block-sum 256 final per-query mins.
__global__ __launch_bounds__(THREADS) void chamfer_stage2(
    const float* __restrict__ minarr, float* __restrict__ blocksum)
{
    const float m = minarr[blockIdx.x * THREADS + threadIdx.x];
    __shared__ float wsum[THREADS / 64];
    const float s = wave_reduce_sum(m);
    if ((threadIdx.x & 63) == 0) wsum[threadIdx.x >> 6] = s;
    __syncthreads();
    if (threadIdx.x == 0) {
        float t = 0.f;
#pragma unroll
        for (int w = 0; w < THREADS / 64; ++w) t += wsum[w];
        blocksum[blockIdx.x] = t;
    }
}

// Stage 3: deterministic final reduction of 512 block sums.
__global__ __launch_bounds__(THREADS) void chamfer_stage3(
    const float* __restrict__ blocksum, float* __restrict__ out)
{
    float v = blocksum[threadIdx.x] + blocksum[threadIdx.x + THREADS];
    __shared__ float wsum[THREADS / 64];
    const float s = wave_reduce_sum(v);
    if ((threadIdx.x & 63) == 0) wsum[threadIdx.x >> 6] = s;
    __syncthreads();
    if (threadIdx.x == 0) {
        float t = 0.f;
#pragma unroll
        for (int w = 0; w < THREADS / 64; ++w) t += wsum[w];
        out[0] = t;
    }
}

extern "C" void kernel_launch(void* const* d_in, const int* in_sizes, int n_in,
                              void* d_out, int out_size, void* d_ws, size_t ws_size,
                              hipStream_t stream) {
    const float* A  = (const float*)d_in[0];   // "input"  [8,8192,3]
    const float* Bp = (const float*)d_in[1];   // "output" [8,8192,3]
    float* out = (float*)d_out;

    float* minarr   = (float*)d_ws;                 // NQ_TOTAL floats = 512 KB
    float* blocksum = minarr + NQ_TOTAL;            // 512 floats

    chamfer_init<<<NQ_TOTAL / THREADS, THREADS, 0, stream>>>(minarr);

    const int nblocks1 = BATCH * 2 * NQB * TSPLIT;  // 2048
    chamfer_stage1<<<nblocks1, THREADS, 0, stream>>>(A, Bp, minarr);

    const int nblocks2 = NQ_TOTAL / THREADS;        // 512
    chamfer_stage2<<<nblocks2, THREADS, 0, stream>>>(minarr, blocksum);

    chamfer_stage3<<<1, THREADS, 0, stream>>>(blocksum, out);
}

// Round 6
// 89.751 us; speedup vs baseline: 1.0231x; 1.0062x over previous
//
#include <hip/hip_runtime.h>

typedef float f32x2 __attribute__((ext_vector_type(2)));
typedef float f32x4 __attribute__((ext_vector_type(4)));

#define BATCH   8
#define NPTS    8192
#define THREADS 256
#define QPT     8                      // queries per thread
#define QBLK    (THREADS * QPT)        // 2048 queries per block
#define NQB     (NPTS / QBLK)          // 4 query-blocks per (batch,dir)
#define TSPLIT  32                     // target-dimension split
#define TSLICE  (NPTS / TSPLIT)        // 256 targets per block
#define NQ_TOTAL (BATCH * 2 * NPTS)    // 131072 total queries

// Init: fill per-query min array with +huge (valid float, any real dist^2 wins).
__global__ __launch_bounds__(THREADS) void chamfer_init(float* __restrict__ minarr) {
    minarr[blockIdx.x * THREADS + threadIdx.x] = 3.4e38f;
}

// Stage 1: for 2048 query points, min of (||b||^2 - 2 a.b) over a
// 256-target slice; result (+||a||^2) merged via atomicMin on int bits
// (exact & order-independent for nonnegative floats -> deterministic).
__global__ __launch_bounds__(THREADS, 4) void chamfer_stage1(
    const float* __restrict__ A,   // [B, N, 3] "input"
    const float* __restrict__ Bp,  // [B, M, 3] "output"
    float* __restrict__ minarr)    // [NQ_TOTAL]
{
    __shared__ __align__(16) float tx[TSLICE];
    __shared__ __align__(16) float ty[TSLICE];
    __shared__ __align__(16) float tz[TSLICE];
    __shared__ __align__(16) float tw[TSLICE];

    const int bid = blockIdx.x;
    const int ts  = bid & (TSPLIT - 1);          // 5 bits
    const int qb  = (bid >> 5) & (NQB - 1);      // 2 bits
    const int bd  = bid >> 7;                    // 0..15  (batch*2 + dir)
    const int b   = bd >> 1;
    const int dir = bd & 1;

    const float* Q = (dir == 0) ? (A  + (size_t)b * NPTS * 3)
                                : (Bp + (size_t)b * NPTS * 3);
    const float* T = (dir == 0) ? (Bp + (size_t)b * NPTS * 3)
                                : (A  + (size_t)b * NPTS * 3);

    const int tid = threadIdx.x;

    // Stage the target slice (SoA) into LDS. TSLICE == THREADS: one element each.
    {
        const int j = ts * TSLICE + tid;
        const float x = T[j * 3 + 0];
        const float y = T[j * 3 + 1];
        const float z = T[j * 3 + 2];
        tx[tid] = x; ty[tid] = y; tz[tid] = z;
        tw[tid] = fmaf(z, z, fmaf(y, y, x * x));
    }

    f32x2 qx[QPT], qy[QPT], qz[QPT];
    float aa[QPT], mn01[QPT], mn23[QPT];
#pragma unroll
    for (int k = 0; k < QPT; ++k) {
        const int q = qb * QBLK + k * THREADS + tid;
        const float x = Q[q * 3 + 0];
        const float y = Q[q * 3 + 1];
        const float z = Q[q * 3 + 2];
        aa[k] = x * x + y * y + z * z;
        const float x2 = -2.0f * x, y2 = -2.0f * y, z2 = -2.0f * z;
        qx[k] = (f32x2){x2, x2};
        qy[k] = (f32x2){y2, y2};
        qz[k] = (f32x2){z2, z2};
        mn01[k] = 3.4e38f;
        mn23[k] = 3.4e38f;
    }

    __syncthreads();

    for (int jj = 0; jj < TSLICE; jj += 4) {
        const f32x4 bx = *(const f32x4*)&tx[jj];   // uniform-addr broadcast reads
        const f32x4 by = *(const f32x4*)&ty[jj];
        const f32x4 bz = *(const f32x4*)&tz[jj];
        const f32x4 bw = *(const f32x4*)&tw[jj];
        const f32x2 bx01 = __builtin_shufflevector(bx, bx, 0, 1);
        const f32x2 bx23 = __builtin_shufflevector(bx, bx, 2, 3);
        const f32x2 by01 = __builtin_shufflevector(by, by, 0, 1);
        const f32x2 by23 = __builtin_shufflevector(by, by, 2, 3);
        const f32x2 bz01 = __builtin_shufflevector(bz, bz, 0, 1);
        const f32x2 bz23 = __builtin_shufflevector(bz, bz, 2, 3);
        const f32x2 bw01 = __builtin_shufflevector(bw, bw, 0, 1);
        const f32x2 bw23 = __builtin_shufflevector(bw, bw, 2, 3);
#pragma unroll
        for (int k = 0; k < QPT; ++k) {
            f32x2 c01 = __builtin_elementwise_fma(qx[k], bx01, bw01);
            c01 = __builtin_elementwise_fma(qy[k], by01, c01);
            c01 = __builtin_elementwise_fma(qz[k], bz01, c01);
            f32x2 c23 = __builtin_elementwise_fma(qx[k], bx23, bw23);
            c23 = __builtin_elementwise_fma(qy[k], by23, c23);
            c23 = __builtin_elementwise_fma(qz[k], bz23, c23);
            mn01[k] = fminf(fminf(c01.x, c01.y), mn01[k]);   // -> v_min3_f32
            mn23[k] = fminf(fminf(c23.x, c23.y), mn23[k]);   // -> v_min3_f32
        }
    }

#pragma unroll
    for (int k = 0; k < QPT; ++k) {
        const int q = qb * QBLK + k * THREADS + tid;
        const int qglobal = bd * NPTS + q;
        const float v = fminf(mn01[k], mn23[k]) + aa[k];     // dist^2 >= 0
        atomicMin((int*)&minarr[qglobal], __float_as_int(v));
    }
}

__device__ inline float wave_reduce_sum(float v) {
#pragma unroll
    for (int off = 32; off; off >>= 1) v += __shfl_down(v, off, 64);
    return v;
}

// Stage 2: block-sum 256 final per-query mins.
__global__ __launch_bounds__(THREADS) void chamfer_stage2(
    const float* __restrict__ minarr, float* __restrict__ blocksum)
{
    const float m = minarr[blockIdx.x * THREADS + threadIdx.x];
    __shared__ float wsum[THREADS / 64];
    const float s = wave_reduce_sum(m);
    if ((threadIdx.x & 63) == 0) wsum[threadIdx.x >> 6] = s;
    __syncthreads();
    if (threadIdx.x == 0) {
        float t = 0.f;
#pragma unroll
        for (int w = 0; w < THREADS / 64; ++w) t += wsum[w];
        blocksum[blockIdx.x] = t;
    }
}

// Stage 3: deterministic final reduction of 512 block sums.
__global__ __launch_bounds__(THREADS) void chamfer_stage3(
    const float* __restrict__ blocksum, float* __restrict__ out)
{
    float v = blocksum[threadIdx.x] + blocksum[threadIdx.x + THREADS];
    __shared__ float wsum[THREADS / 64];
    const float s = wave_reduce_sum(v);
    if ((threadIdx.x & 63) == 0) wsum[threadIdx.x >> 6] = s;
    __syncthreads();
    if (threadIdx.x == 0) {
        float t = 0.f;
#pragma unroll
        for (int w = 0; w < THREADS / 64; ++w) t += wsum[w];
        out[0] = t;
    }
}

extern "C" void kernel_launch(void* const* d_in, const int* in_sizes, int n_in,
                              void* d_out, int out_size, void* d_ws, size_t ws_size,
                              hipStream_t stream) {
    const float* A  = (const float*)d_in[0];   // "input"  [8,8192,3]
    const float* Bp = (const float*)d_in[1];   // "output" [8,8192,3]
    float* out = (float*)d_out;

    float* minarr   = (float*)d_ws;                 // NQ_TOTAL floats = 512 KB
    float* blocksum = minarr + NQ_TOTAL;            // 512 floats

    chamfer_init<<<NQ_TOTAL / THREADS, THREADS, 0, stream>>>(minarr);

    const int nblocks1 = BATCH * 2 * NQB * TSPLIT;  // 2048
    chamfer_stage1<<<nblocks1, THREADS, 0, stream>>>(A, Bp, minarr);

    const int nblocks2 = NQ_TOTAL / THREADS;        // 512
    chamfer_stage2<<<nblocks2, THREADS, 0, stream>>>(minarr, blocksum);

    chamfer_stage3<<<1, THREADS, 0, stream>>>(blocksum, out);
}

// Round 7
// 64.103 us; speedup vs baseline: 1.4324x; 1.4001x over previous
//
#include <hip/hip_runtime.h>

typedef short bf16x8 __attribute__((ext_vector_type(8)));
typedef float f32x16 __attribute__((ext_vector_type(16)));

#define BATCH    8
#define NPTS     8192
#define THREADS  256
#define NQ_TOTAL (BATCH * 2 * NPTS)   // 131072
#define TSLICE   2048                 // targets staged per LDS slice (32 KB)

__device__ __forceinline__ unsigned short f2bf(float f) {   // fp32 -> bf16 RNE
    unsigned u = __builtin_bit_cast(unsigned, f);
    u += 0x7FFFu + ((u >> 16) & 1u);
    return (unsigned short)(u >> 16);
}
__device__ __forceinline__ float bf2f(unsigned short h) {
    return __builtin_bit_cast(float, (unsigned)h << 16);
}
__device__ __forceinline__ float min3f(float a, float b, float c) {
    float d; asm("v_min3_f32 %0, %1, %2, %3" : "=v"(d) : "v"(a), "v"(b), "v"(c)); return d;
}

// Pack every point (both arrays) into its 8-bf16 target fragment:
// [xh, yh, zh, xl, yl, zl, bbh, bbl]  (hi/lo bf16 split, bb = ||p||^2 fp32-split)
__global__ __launch_bounds__(THREADS) void chamfer_pack(
    const float* __restrict__ A, const float* __restrict__ Bp, short* __restrict__ pk)
{
    const int i = blockIdx.x * THREADS + threadIdx.x;          // 0..131071
    const float* p = (i < BATCH * NPTS) ? (A + (size_t)i * 3)
                                        : (Bp + (size_t)(i - BATCH * NPTS) * 3);
    const float x = p[0], y = p[1], z = p[2];
    const unsigned short xh = f2bf(x), yh = f2bf(y), zh = f2bf(z);
    const unsigned short xl = f2bf(x - bf2f(xh));
    const unsigned short yl = f2bf(y - bf2f(yh));
    const unsigned short zl = f2bf(z - bf2f(zh));
    const float bb = fmaf(z, z, fmaf(y, y, x * x));
    const unsigned short bh = f2bf(bb);
    const unsigned short bl = f2bf(bb - bf2f(bh));
    bf16x8 v = {(short)xh, (short)yh, (short)zh, (short)xl,
                (short)yl, (short)zl, (short)bh, (short)bl};
    ((bf16x8*)pk)[i] = v;
}

// Stage 1: each wave owns 64 queries (2 col-groups of 32), streams all 8192
// targets of its (batch,dir) via LDS in 32KB slices. One 32x32x16 bf16 MFMA
// per (32-target tile x 32-query group): D[t][q] = bb_t - 2 a_q.b_t (split-
// bf16 exact to ~3e-5). Per-lane min over 16 acc regs (rows) + xor-32 merge.
__global__ __launch_bounds__(THREADS) void chamfer_stage1(
    const float* __restrict__ A, const float* __restrict__ Bp,
    const short* __restrict__ pk, float* __restrict__ minq)
{
    __shared__ short lds[TSLICE * 8];

    const int bid    = blockIdx.x;          // 512 blocks
    const int qchunk = bid & 31;
    const int bd     = bid >> 5;            // 0..15
    const int b      = bd >> 1, dir = bd & 1;

    const float*  Q    = (dir == 0) ? (A + (size_t)b * NPTS * 3)
                                    : (Bp + (size_t)b * NPTS * 3);
    const bf16x8* tsrc = (const bf16x8*)pk +
                         (dir == 0 ? (BATCH * NPTS + b * NPTS) : (b * NPTS));

    const int tid  = threadIdx.x;
    const int wave = tid >> 6, lane = tid & 63;
    const int col  = lane & 31, g = lane >> 5;
    const int qbase = qchunk * 256 + wave * 64;

    // Build per-lane query (B-side) fragments for the two 32-query groups.
    bf16x8 qf[2]; float aa[2];
#pragma unroll
    for (int j = 0; j < 2; ++j) {
        const int q  = qbase + j * 32 + col;
        const float x = Q[q * 3 + 0], y = Q[q * 3 + 1], z = Q[q * 3 + 2];
        aa[j] = fmaf(z, z, fmaf(y, y, x * x));
        const float sx = -2.f * x, sy = -2.f * y, sz = -2.f * z;
        const unsigned short xh = f2bf(sx), yh = f2bf(sy), zh = f2bf(sz);
        const unsigned short xl = f2bf(sx - bf2f(xh));
        const unsigned short yl = f2bf(sy - bf2f(yh));
        const unsigned short zl = f2bf(sz - bf2f(zh));
        const short ONE = (short)0x3F80;          // bf16 1.0
        bf16x8 v0 = {(short)xh, (short)yh, (short)zh,
                     (short)xh, (short)yh, (short)zh, ONE, ONE};
        bf16x8 v1 = {(short)xl, (short)yl, (short)zl, 0, 0, 0, 0, 0};
        qf[j] = g ? v1 : v0;
    }

    float mnA[2] = {3.4e38f, 3.4e38f}, mnB[2] = {3.4e38f, 3.4e38f};
    bf16x8* ldsv = (bf16x8*)lds;

    for (int s = 0; s < NPTS; s += TSLICE) {
        __syncthreads();
#pragma unroll
        for (int u = 0; u < TSLICE / THREADS; ++u) {
            const int idx = u * THREADS + tid;
            ldsv[idx] = tsrc[s + idx];            // global b128 -> ds_write_b128
        }
        __syncthreads();

#pragma unroll 2
        for (int t = 0; t < TSLICE / 32; ++t) {
            const bf16x8 af = ldsv[t * 32 + col]; // ds_read_b128, 2-lane alias free
#pragma unroll
            for (int j = 0; j < 2; ++j) {
                f32x16 acc = __builtin_amdgcn_mfma_f32_32x32x16_bf16(
                    af, qf[j],
                    (f32x16){0.f,0.f,0.f,0.f,0.f,0.f,0.f,0.f,
                             0.f,0.f,0.f,0.f,0.f,0.f,0.f,0.f}, 0, 0, 0);
                mnA[j] = min3f(acc[0],  acc[1],  mnA[j]);
                mnA[j] = min3f(acc[2],  acc[3],  mnA[j]);
                mnA[j] = min3f(acc[4],  acc[5],  mnA[j]);
                mnA[j] = min3f(acc[6],  acc[7],  mnA[j]);
                mnB[j] = min3f(acc[8],  acc[9],  mnB[j]);
                mnB[j] = min3f(acc[10], acc[11], mnB[j]);
                mnB[j] = min3f(acc[12], acc[13], mnB[j]);
                mnB[j] = min3f(acc[14], acc[15], mnB[j]);
            }
        }
    }

#pragma unroll
    for (int j = 0; j < 2; ++j) {
        float m = fminf(mnA[j], mnB[j]);
        m = fminf(m, __shfl_xor(m, 32, 64));      // merge row-halves
        if (g == 0)
            minq[bd * NPTS + qbase + j * 32 + col] = m + aa[j];
    }
}

__device__ inline float wave_reduce_sum(float v) {
#pragma unroll
    for (int off = 32; off; off >>= 1) v += __shfl_down(v, off, 64);
    return v;
}

// Stage 2: block-sum 256 per-query mins.
__global__ __launch_bounds__(THREADS) void chamfer_stage2(
    const float* __restrict__ minq, float* __restrict__ blocksum)
{
    const float m = minq[blockIdx.x * THREADS + threadIdx.x];
    __shared__ float wsum[THREADS / 64];
    const float s = wave_reduce_sum(m);
    if ((threadIdx.x & 63) == 0) wsum[threadIdx.x >> 6] = s;
    __syncthreads();
    if (threadIdx.x == 0) {
        float t = 0.f;
#pragma unroll
        for (int w = 0; w < THREADS / 64; ++w) t += wsum[w];
        blocksum[blockIdx.x] = t;
    }
}

// Stage 3: deterministic final reduction of 512 block sums.
__global__ __launch_bounds__(THREADS) void chamfer_stage3(
    const float* __restrict__ blocksum, float* __restrict__ out)
{
    float v = blocksum[threadIdx.x] + blocksum[threadIdx.x + THREADS];
    __shared__ float wsum[THREADS / 64];
    const float s = wave_reduce_sum(v);
    if ((threadIdx.x & 63) == 0) wsum[threadIdx.x >> 6] = s;
    __syncthreads();
    if (threadIdx.x == 0) {
        float t = 0.f;
#pragma unroll
        for (int w = 0; w < THREADS / 64; ++w) t += wsum[w];
        out[0] = t;
    }
}

extern "C" void kernel_launch(void* const* d_in, const int* in_sizes, int n_in,
                              void* d_out, int out_size, void* d_ws, size_t ws_size,
                              hipStream_t stream) {
    const float* A  = (const float*)d_in[0];   // "input"  [8,8192,3]
    const float* Bp = (const float*)d_in[1];   // "output" [8,8192,3]
    float* out = (float*)d_out;

    short* pk       = (short*)d_ws;                              // 2 MB packed frags
    float* minq     = (float*)((char*)d_ws + (size_t)NQ_TOTAL * 16);  // 512 KB
    float* blocksum = minq + NQ_TOTAL;                           // 512 floats

    chamfer_pack  <<<NQ_TOTAL / THREADS, THREADS, 0, stream>>>(A, Bp, pk);   // 512
    chamfer_stage1<<<512, THREADS, 0, stream>>>(A, Bp, pk, minq);
    chamfer_stage2<<<NQ_TOTAL / THREADS / 1, THREADS, 0, stream>>>(minq, blocksum); // 512
    chamfer_stage3<<<1, THREADS, 0, stream>>>(blocksum, out);
}

// Round 8
// 60.103 us; speedup vs baseline: 1.5277x; 1.0666x over previous
//
#include <hip/hip_runtime.h>

typedef short bf16x8 __attribute__((ext_vector_type(8)));
typedef float f32x16 __attribute__((ext_vector_type(16)));

#define BATCH    8
#define NPTS     8192
#define THREADS  256
#define NQ_TOTAL (BATCH * 2 * NPTS)   // 131072
#define TSPLIT   8
#define TSLICE   (NPTS / TSPLIT)      // 1024 targets per block (16 KB LDS)
#define NJ       4                    // query groups per wave (128 queries/wave)

__device__ __forceinline__ unsigned short f2bf(float f) {   // fp32 -> bf16 RNE
    unsigned u = __builtin_bit_cast(unsigned, f);
    u += 0x7FFFu + ((u >> 16) & 1u);
    return (unsigned short)(u >> 16);
}
__device__ __forceinline__ float bf2f(unsigned short h) {
    return __builtin_bit_cast(float, (unsigned)h << 16);
}
__device__ __forceinline__ float min3f(float a, float b, float c) {
    float d; asm("v_min3_f32 %0, %1, %2, %3" : "=v"(d) : "v"(a), "v"(b), "v"(c)); return d;
}

// Init: fill per-query min array with +huge.
__global__ __launch_bounds__(THREADS) void chamfer_init(float* __restrict__ minq) {
    minq[blockIdx.x * THREADS + threadIdx.x] = 3.4e38f;
}

// Pack every point (both arrays) into its 8-bf16 target fragment:
// [xh, yh, zh, xl, yl, zl, bbh, bbl]  (hi/lo bf16 split, bb = ||p||^2 fp32-split)
__global__ __launch_bounds__(THREADS) void chamfer_pack(
    const float* __restrict__ A, const float* __restrict__ Bp, short* __restrict__ pk)
{
    const int i = blockIdx.x * THREADS + threadIdx.x;          // 0..131071
    const float* p = (i < BATCH * NPTS) ? (A + (size_t)i * 3)
                                        : (Bp + (size_t)(i - BATCH * NPTS) * 3);
    const float x = p[0], y = p[1], z = p[2];
    const unsigned short xh = f2bf(x), yh = f2bf(y), zh = f2bf(z);
    const unsigned short xl = f2bf(x - bf2f(xh));
    const unsigned short yl = f2bf(y - bf2f(yh));
    const unsigned short zl = f2bf(z - bf2f(zh));
    const float bb = fmaf(z, z, fmaf(y, y, x * x));
    const unsigned short bh = f2bf(bb);
    const unsigned short bl = f2bf(bb - bf2f(bh));
    bf16x8 v = {(short)xh, (short)yh, (short)zh, (short)xl,
                (short)yl, (short)zl, (short)bh, (short)bl};
    ((bf16x8*)pk)[i] = v;
}

// Stage 1: each wave owns 128 queries (4 col-groups of 32) and one
// 1024-target slice (staged once in LDS). One 32x32x16 bf16 MFMA per
// (32-target tile x 32-query group): D[t][q] = bb_t - 2 a_q.b_t
// (split-bf16, error ~3e-5). Min over 16 acc regs + xor-32 merge; merged
// across target-slices via atomicMin on int bits (exact, order-indep).
__global__ __launch_bounds__(THREADS) void chamfer_stage1(
    const float* __restrict__ A, const float* __restrict__ Bp,
    const short* __restrict__ pk, float* __restrict__ minq)
{
    __shared__ short lds[TSLICE * 8];

    const int bid    = blockIdx.x;          // 2048 blocks
    const int ts     = bid & (TSPLIT - 1);  // 3 bits
    const int qchunk = (bid >> 3) & 15;     // 4 bits
    const int bd     = bid >> 7;            // 0..15
    const int b      = bd >> 1, dir = bd & 1;

    const float*  Q    = (dir == 0) ? (A + (size_t)b * NPTS * 3)
                                    : (Bp + (size_t)b * NPTS * 3);
    const bf16x8* tsrc = (const bf16x8*)pk +
                         (dir == 0 ? (BATCH * NPTS + b * NPTS) : (b * NPTS));

    const int tid  = threadIdx.x;
    const int wave = tid >> 6, lane = tid & 63;
    const int col  = lane & 31, g = lane >> 5;
    const int qbase = qchunk * 512 + wave * 128;

    // Stage this block's target slice (SoA frags) into LDS.
    bf16x8* ldsv = (bf16x8*)lds;
    const int sbase = ts * TSLICE;
#pragma unroll
    for (int u = 0; u < TSLICE / THREADS; ++u) {
        const int idx = u * THREADS + tid;
        ldsv[idx] = tsrc[sbase + idx];
    }

    // Per-lane query (B-side) fragments for the four 32-query groups.
    bf16x8 qf[NJ]; float aa[NJ];
#pragma unroll
    for (int j = 0; j < NJ; ++j) {
        const int q  = qbase + j * 32 + col;
        const float x = Q[q * 3 + 0], y = Q[q * 3 + 1], z = Q[q * 3 + 2];
        aa[j] = fmaf(z, z, fmaf(y, y, x * x));
        const float sx = -2.f * x, sy = -2.f * y, sz = -2.f * z;
        const unsigned short xh = f2bf(sx), yh = f2bf(sy), zh = f2bf(sz);
        const unsigned short xl = f2bf(sx - bf2f(xh));
        const unsigned short yl = f2bf(sy - bf2f(yh));
        const unsigned short zl = f2bf(sz - bf2f(zh));
        const short ONE = (short)0x3F80;          // bf16 1.0
        bf16x8 v0 = {(short)xh, (short)yh, (short)zh,
                     (short)xh, (short)yh, (short)zh, ONE, ONE};
        bf16x8 v1 = {(short)xl, (short)yl, (short)zl, 0, 0, 0, 0, 0};
        qf[j] = g ? v1 : v0;
    }

    float mnA[NJ], mnB[NJ];
#pragma unroll
    for (int j = 0; j < NJ; ++j) { mnA[j] = 3.4e38f; mnB[j] = 3.4e38f; }

    __syncthreads();

#pragma unroll 2
    for (int t = 0; t < TSLICE / 32; ++t) {
        const bf16x8 af = ldsv[t * 32 + col];     // ds_read_b128 (2-lane alias, free)
#pragma unroll
        for (int j = 0; j < NJ; ++j) {
            f32x16 acc = __builtin_amdgcn_mfma_f32_32x32x16_bf16(
                af, qf[j],
                (f32x16){0.f,0.f,0.f,0.f,0.f,0.f,0.f,0.f,
                         0.f,0.f,0.f,0.f,0.f,0.f,0.f,0.f}, 0, 0, 0);
            mnA[j] = min3f(acc[0],  acc[1],  mnA[j]);
            mnA[j] = min3f(acc[2],  acc[3],  mnA[j]);
            mnA[j] = min3f(acc[4],  acc[5],  mnA[j]);
            mnA[j] = min3f(acc[6],  acc[7],  mnA[j]);
            mnB[j] = min3f(acc[8],  acc[9],  mnB[j]);
            mnB[j] = min3f(acc[10], acc[11], mnB[j]);
            mnB[j] = min3f(acc[12], acc[13], mnB[j]);
            mnB[j] = min3f(acc[14], acc[15], mnB[j]);
        }
    }

#pragma unroll
    for (int j = 0; j < NJ; ++j) {
        float m = fminf(mnA[j], mnB[j]);
        m = fminf(m, __shfl_xor(m, 32, 64));      // merge row-halves
        if (g == 0)
            atomicMin((int*)&minq[bd * NPTS + qbase + j * 32 + col],
                      __float_as_int(m + aa[j]));
    }
}

__device__ inline float wave_reduce_sum(float v) {
#pragma unroll
    for (int off = 32; off; off >>= 1) v += __shfl_down(v, off, 64);
    return v;
}

// Stage 2: block-sum 256 per-query mins.
__global__ __launch_bounds__(THREADS) void chamfer_stage2(
    const float* __restrict__ minq, float* __restrict__ blocksum)
{
    const float m = minq[blockIdx.x * THREADS + threadIdx.x];
    __shared__ float wsum[THREADS / 64];
    const float s = wave_reduce_sum(m);
    if ((threadIdx.x & 63) == 0) wsum[threadIdx.x >> 6] = s;
    __syncthreads();
    if (threadIdx.x == 0) {
        float t = 0.f;
#pragma unroll
        for (int w = 0; w < THREADS / 64; ++w) t += wsum[w];
        blocksum[blockIdx.x] = t;
    }
}

// Stage 3: deterministic final reduction of 512 block sums.
__global__ __launch_bounds__(THREADS) void chamfer_stage3(
    const float* __restrict__ blocksum, float* __restrict__ out)
{
    float v = blocksum[threadIdx.x] + blocksum[threadIdx.x + THREADS];
    __shared__ float wsum[THREADS / 64];
    const float s = wave_reduce_sum(v);
    if ((threadIdx.x & 63) == 0) wsum[threadIdx.x >> 6] = s;
    __syncthreads();
    if (threadIdx.x == 0) {
        float t = 0.f;
#pragma unroll
        for (int w = 0; w < THREADS / 64; ++w) t += wsum[w];
        out[0] = t;
    }
}

extern "C" void kernel_launch(void* const* d_in, const int* in_sizes, int n_in,
                              void* d_out, int out_size, void* d_ws, size_t ws_size,
                              hipStream_t stream) {
    const float* A  = (const float*)d_in[0];   // "input"  [8,8192,3]
    const float* Bp = (const float*)d_in[1];   // "output" [8,8192,3]
    float* out = (float*)d_out;

    short* pk       = (short*)d_ws;                                   // 2 MB packed frags
    float* minq     = (float*)((char*)d_ws + (size_t)NQ_TOTAL * 16);  // 512 KB
    float* blocksum = minq + NQ_TOTAL;                                // 512 floats

    chamfer_init  <<<NQ_TOTAL / THREADS, THREADS, 0, stream>>>(minq);        // 512
    chamfer_pack  <<<NQ_TOTAL / THREADS, THREADS, 0, stream>>>(A, Bp, pk);   // 512

    const int nblocks1 = BATCH * 2 * 16 * TSPLIT;                            // 2048
    chamfer_stage1<<<nblocks1, THREADS, 0, stream>>>(A, Bp, pk, minq);

    chamfer_stage2<<<NQ_TOTAL / THREADS, THREADS, 0, stream>>>(minq, blocksum); // 512
    chamfer_stage3<<<1, THREADS, 0, stream>>>(blocksum, out);
}

// Round 10
// 45.341 us; speedup vs baseline: 2.0251x; 1.3256x over previous
//
#include <hip/hip_runtime.h>

typedef short bf16x8 __attribute__((ext_vector_type(8)));
typedef float f32x16 __attribute__((ext_vector_type(16)));

#define BATCH    8
#define NPTS     8192
#define THREADS  256
#define NQ_TOTAL (BATCH * 2 * NPTS)   // 131072
#define TSPLIT   8
#define TSLICE   (NPTS / TSPLIT)      // 1024 targets per block (16 KB LDS)
#define NJ       4                    // query groups per wave (128 queries/wave)

__device__ __forceinline__ unsigned short f2bf(float f) {   // fp32 -> bf16 RNE
    unsigned u = __builtin_bit_cast(unsigned, f);
    u += 0x7FFFu + ((u >> 16) & 1u);
    return (unsigned short)(u >> 16);
}
__device__ __forceinline__ float bf2f(unsigned short h) {
    return __builtin_bit_cast(float, (unsigned)h << 16);
}

// Init: fill per-query min array with +huge.
__global__ __launch_bounds__(THREADS) void chamfer_init(float* __restrict__ minq) {
    minq[blockIdx.x * THREADS + threadIdx.x] = 3.4e38f;
}

// Pack every point (both arrays) into its 8-bf16 target fragment:
// [xh, yh, zh, xl, yl, zl, bbh, bbl]  (hi/lo bf16 split, bb = ||p||^2 fp32-split)
__global__ __launch_bounds__(THREADS) void chamfer_pack(
    const float* __restrict__ A, const float* __restrict__ Bp, short* __restrict__ pk)
{
    const int i = blockIdx.x * THREADS + threadIdx.x;          // 0..131071
    const float* p = (i < BATCH * NPTS) ? (A + (size_t)i * 3)
                                        : (Bp + (size_t)(i - BATCH * NPTS) * 3);
    const float x = p[0], y = p[1], z = p[2];
    const unsigned short xh = f2bf(x), yh = f2bf(y), zh = f2bf(z);
    const unsigned short xl = f2bf(x - bf2f(xh));
    const unsigned short yl = f2bf(y - bf2f(yh));
    const unsigned short zl = f2bf(z - bf2f(zh));
    const float bb = fmaf(z, z, fmaf(y, y, x * x));
    const unsigned short bh = f2bf(bb);
    const unsigned short bl = f2bf(bb - bf2f(bh));
    bf16x8 v = {(short)xh, (short)yh, (short)zh, (short)xl,
                (short)yl, (short)zl, (short)bh, (short)bl};
    ((bf16x8*)pk)[i] = v;
}

// Stage 1: each wave owns 128 queries (4 col-groups of 32) and one
// 1024-target slice (staged once in LDS). One 32x32x16 bf16 MFMA per
// (32-target tile x 32-query group): D[t][q] = bb_t - 2 a_q.b_t
// (split-bf16, error ~3e-5). Min via fminf chains (compiler fuses to
// v_min3_f32 and handles MFMA->VALU hazards itself; NO inline asm may
// read MFMA destination registers -- that miscompiled in R9).
// __launch_bounds__(256,2): 128-VGPR budget keeps acc in arch VGPRs
// (R8's default gave VGPR=28 -> AGPR accumulators -> accvgpr_read per use).
__global__ __launch_bounds__(THREADS, 2) void chamfer_stage1(
    const float* __restrict__ A, const float* __restrict__ Bp,
    const short* __restrict__ pk, float* __restrict__ minq)
{
    __shared__ short lds[TSLICE * 8];

    const int bid    = blockIdx.x;          // 2048 blocks
    const int ts     = bid & (TSPLIT - 1);  // 3 bits
    const int qchunk = (bid >> 3) & 15;     // 4 bits
    const int bd     = bid >> 7;            // 0..15
    const int b      = bd >> 1, dir = bd & 1;

    const float*  Q    = (dir == 0) ? (A + (size_t)b * NPTS * 3)
                                    : (Bp + (size_t)b * NPTS * 3);
    const bf16x8* tsrc = (const bf16x8*)pk +
                         (dir == 0 ? (BATCH * NPTS + b * NPTS) : (b * NPTS));

    const int tid  = threadIdx.x;
    const int wave = tid >> 6, lane = tid & 63;
    const int col  = lane & 31, g = lane >> 5;
    const int qbase = qchunk * 512 + wave * 128;

    // Stage this block's target slice (SoA frags) into LDS.
    bf16x8* ldsv = (bf16x8*)lds;
    const int sbase = ts * TSLICE;
#pragma unroll
    for (int u = 0; u < TSLICE / THREADS; ++u) {
        const int idx = u * THREADS + tid;
        ldsv[idx] = tsrc[sbase + idx];
    }

    // Per-lane query (B-side) fragments for the four 32-query groups.
    bf16x8 qf[NJ]; float aa[NJ];
#pragma unroll
    for (int j = 0; j < NJ; ++j) {
        const int q  = qbase + j * 32 + col;
        const float x = Q[q * 3 + 0], y = Q[q * 3 + 1], z = Q[q * 3 + 2];
        aa[j] = fmaf(z, z, fmaf(y, y, x * x));
        const float sx = -2.f * x, sy = -2.f * y, sz = -2.f * z;
        const unsigned short xh = f2bf(sx), yh = f2bf(sy), zh = f2bf(sz);
        const unsigned short xl = f2bf(sx - bf2f(xh));
        const unsigned short yl = f2bf(sy - bf2f(yh));
        const unsigned short zl = f2bf(sz - bf2f(zh));
        const short ONE = (short)0x3F80;          // bf16 1.0
        bf16x8 v0 = {(short)xh, (short)yh, (short)zh,
                     (short)xh, (short)yh, (short)zh, ONE, ONE};
        bf16x8 v1 = {(short)xl, (short)yl, (short)zl, 0, 0, 0, 0, 0};
        qf[j] = g ? v1 : v0;
    }

    const f32x16 kZero = {0.f,0.f,0.f,0.f,0.f,0.f,0.f,0.f,
                          0.f,0.f,0.f,0.f,0.f,0.f,0.f,0.f};   // hoisted C

    float mnA[NJ], mnB[NJ];
#pragma unroll
    for (int j = 0; j < NJ; ++j) { mnA[j] = 3.4e38f; mnB[j] = 3.4e38f; }

    __syncthreads();

#pragma unroll 2
    for (int t = 0; t < TSLICE / 32; ++t) {
        const bf16x8 af = ldsv[t * 32 + col];     // ds_read_b128 (2-lane alias, free)
#pragma unroll
        for (int j = 0; j < NJ; ++j) {
            f32x16 acc = __builtin_amdgcn_mfma_f32_32x32x16_bf16(
                af, qf[j], kZero, 0, 0, 0);
            mnA[j] = fminf(fminf(acc[0],  acc[1]),  mnA[j]);   // -> v_min3_f32
            mnA[j] = fminf(fminf(acc[2],  acc[3]),  mnA[j]);
            mnA[j] = fminf(fminf(acc[4],  acc[5]),  mnA[j]);
            mnA[j] = fminf(fminf(acc[6],  acc[7]),  mnA[j]);
            mnB[j] = fminf(fminf(acc[8],  acc[9]),  mnB[j]);
            mnB[j] = fminf(fminf(acc[10], acc[11]), mnB[j]);
            mnB[j] = fminf(fminf(acc[12], acc[13]), mnB[j]);
            mnB[j] = fminf(fminf(acc[14], acc[15]), mnB[j]);
        }
    }

#pragma unroll
    for (int j = 0; j < NJ; ++j) {
        float m = fminf(mnA[j], mnB[j]);
        m = fminf(m, __shfl_xor(m, 32, 64));      // merge row-halves
        if (g == 0)
            atomicMin((int*)&minq[bd * NPTS + qbase + j * 32 + col],
                      __float_as_int(m + aa[j]));
    }
}

__device__ inline float wave_reduce_sum(float v) {
#pragma unroll
    for (int off = 32; off; off >>= 1) v += __shfl_down(v, off, 64);
    return v;
}

// Stage 2: block-sum 256 per-query mins.
__global__ __launch_bounds__(THREADS) void chamfer_stage2(
    const float* __restrict__ minq, float* __restrict__ blocksum)
{
    const float m = minq[blockIdx.x * THREADS + threadIdx.x];
    __shared__ float wsum[THREADS / 64];
    const float s = wave_reduce_sum(m);
    if ((threadIdx.x & 63) == 0) wsum[threadIdx.x >> 6] = s;
    __syncthreads();
    if (threadIdx.x == 0) {
        float t = 0.f;
#pragma unroll
        for (int w = 0; w < THREADS / 64; ++w) t += wsum[w];
        blocksum[blockIdx.x] = t;
    }
}

// Stage 3: deterministic final reduction of 512 block sums.
__global__ __launch_bounds__(THREADS) void chamfer_stage3(
    const float* __restrict__ blocksum, float* __restrict__ out)
{
    float v = blocksum[threadIdx.x] + blocksum[threadIdx.x + THREADS];
    __shared__ float wsum[THREADS / 64];
    const float s = wave_reduce_sum(v);
    if ((threadIdx.x & 63) == 0) wsum[threadIdx.x >> 6] = s;
    __syncthreads();
    if (threadIdx.x == 0) {
        float t = 0.f;
#pragma unroll
        for (int w = 0; w < THREADS / 64; ++w) t += wsum[w];
        out[0] = t;
    }
}

extern "C" void kernel_launch(void* const* d_in, const int* in_sizes, int n_in,
                              void* d_out, int out_size, void* d_ws, size_t ws_size,
                              hipStream_t stream) {
    const float* A  = (const float*)d_in[0];   // "input"  [8,8192,3]
    const float* Bp = (const float*)d_in[1];   // "output" [8,8192,3]
    float* out = (float*)d_out;

    short* pk       = (short*)d_ws;                                   // 2 MB packed frags
    float* minq     = (float*)((char*)d_ws + (size_t)NQ_TOTAL * 16);  // 512 KB
    float* blocksum = minq + NQ_TOTAL;                                // 512 floats

    chamfer_init  <<<NQ_TOTAL / THREADS, THREADS, 0, stream>>>(minq);        // 512
    chamfer_pack  <<<NQ_TOTAL / THREADS, THREADS, 0, stream>>>(A, Bp, pk);   // 512

    const int nblocks1 = BATCH * 2 * 16 * TSPLIT;                            // 2048
    chamfer_stage1<<<nblocks1, THREADS, 0, stream>>>(A, Bp, pk, minq);

    chamfer_stage2<<<NQ_TOTAL / THREADS, THREADS, 0, stream>>>(minq, blocksum); // 512
    chamfer_stage3<<<1, THREADS, 0, stream>>>(blocksum, out);
}